// Round 11
// baseline (841.147 us; speedup 1.0000x reference)
//
#include <hip/hip_runtime.h>
#include <hip/hip_fp16.h>

// ScreenedCoulombEnergy on MI355X — v7 = v6 production (unchanged, anchor
// pair_bins ~176us) + ABLATION PROBES. (Second resubmit: R9 and R10 were both
// GPUAcquisitionTimeout — never measured.) Three rounds of model-mismatch
// demand decomposition (Common-mistake #8: ablate before optimizing). Probes
// are sized to exceed pair_bins so they appear in the top-5 dispatch table:
//   probe_streams: 6 full passes of the 3 coalesced streams only.
//   probe_gather : 3 passes of streams + 2 divergent tab gathers + math.
// Probe sinks write into the partial region, which pair_bins fully
// overwrites afterwards -> production output unaffected.

constexpr float RADIUS = 5.0f;
constexpr float ECONV  = 14.399645f;
#define NMOL 2048

typedef float f4 __attribute__((ext_vector_type(4)));
typedef int   i4 __attribute__((ext_vector_type(4)));

// tab[i] = (mol[i] << 16) | f16_bits(q[i])
__global__ __launch_bounds__(256) void prep_tab(const float* __restrict__ q,
                                                const int* __restrict__ mol,
                                                unsigned* __restrict__ tab, int n) {
    int i = blockIdx.x * 256 + threadIdx.x;
    if (i < n) {
        unsigned qb = __half_as_ushort(__float2half(q[i]));
        tab[i] = ((unsigned)mol[i] << 16) | qb;
    }
}

// PROBE A: pure 3-stream read, 6 passes, no gathers/LDS/atomics.
__global__ __launch_bounds__(256) void probe_streams(
    const f4* __restrict__ dist4, const i4* __restrict__ first4,
    const i4* __restrict__ second4, float* __restrict__ sink, int nvec)
{
    const int T = gridDim.x * 256;
    const int t0 = blockIdx.x * 256 + threadIdx.x;
    float fa = 0.f; int ia = 0;
#pragma unroll 1
    for (int pass = 0; pass < 6; ++pass) {
#pragma unroll 1
        for (int v = t0; v < nvec; v += T) {
            f4 d = dist4[v]; i4 f = first4[v]; i4 s = second4[v];
            fa += d[0] + d[1] + d[2] + d[3];
            ia += f[0] + f[1] + f[2] + f[3] + s[0] + s[1] + s[2] + s[3];
        }
    }
    sink[t0] = fa + (float)ia;
}

// PROBE B: streams + 2 divergent gathers/pair + full math, register acc,
// no LDS bins. 3 passes.
__global__ __launch_bounds__(256) void probe_gather(
    const f4* __restrict__ dist4, const i4* __restrict__ first4,
    const i4* __restrict__ second4, const unsigned* __restrict__ tab,
    float* __restrict__ sink, int nvec)
{
    const float c_rad = 3.14159265358979323846f / RADIUS;
    const int T = gridDim.x * 256;
    const int t0 = blockIdx.x * 256 + threadIdx.x;
    float acc = 0.f;
#pragma unroll 1
    for (int pass = 0; pass < 3; ++pass) {
#pragma unroll 1
        for (int v = t0; v < nvec; v += T) {
            f4 d = dist4[v]; i4 f = first4[v]; i4 s = second4[v];
            unsigned tf[4], ts[4];
#pragma unroll
            for (int k = 0; k < 4; ++k) { tf[k] = tab[f[k]]; ts[k] = tab[s[k]]; }
#pragma unroll
            for (int k = 0; k < 4; ++k) {
                float qi = __half2float(__ushort_as_half((ushort)(tf[k] & 0xffffu)));
                float qj = __half2float(__ushort_as_half((ushort)(ts[k] & 0xffffu)));
                float dd = d[k];
                float scr = (dd < RADIUS) ? 0.5f * (1.0f + __cosf(dd * c_rad)) : 0.0f;
                acc += qi * qj * __fdividef(scr, dd) + (float)(tf[k] >> 16);
            }
        }
    }
    sink[t0] = acc;
}

// ---- production (v6, unchanged) ----
__global__ __launch_bounds__(256, 6) void pair_bins(
    const f4* __restrict__ dist4,
    const i4* __restrict__ first4,
    const i4* __restrict__ second4,
    const unsigned* __restrict__ tab,
    float* __restrict__ partial,
    int nvec, int n_mol)
{
    __shared__ float bins[NMOL];
    for (int m = threadIdx.x; m < NMOL; m += 256) bins[m] = 0.0f;
    __syncthreads();

    const float c_rad = 3.14159265358979323846f / RADIUS;
    const int T = gridDim.x * 256;
    int v = blockIdx.x * 256 + threadIdx.x;

    for (; v < nvec; v += 2 * T) {
        const bool hasB = (v + T) < nvec;
        const int vb = hasB ? v + T : v;
        f4 da = dist4[v];   i4 fa = first4[v];   i4 sa = second4[v];
        f4 db = dist4[vb];  i4 fb = first4[vb];  i4 sb = second4[vb];

        unsigned tfa[4], tsa[4], tfb[4], tsb[4];
#pragma unroll
        for (int k = 0; k < 4; ++k) { tfa[k] = tab[fa[k]]; tsa[k] = tab[sa[k]]; }
#pragma unroll
        for (int k = 0; k < 4; ++k) { tfb[k] = tab[fb[k]]; tsb[k] = tab[sb[k]]; }

#pragma unroll
        for (int k = 0; k < 4; ++k) {
            const float qi = __half2float(__ushort_as_half((ushort)(tfa[k] & 0xffffu)));
            const float qj = __half2float(__ushort_as_half((ushort)(tsa[k] & 0xffffu)));
            const int   mi = (int)(tfa[k] >> 16);
            const float d  = da[k];
            const float scr = (d < RADIUS) ? 0.5f * (1.0f + __cosf(d * c_rad)) : 0.0f;
            atomicAdd(&bins[mi], qi * qj * __fdividef(scr, d));
        }
        if (hasB) {
#pragma unroll
            for (int k = 0; k < 4; ++k) {
                const float qi = __half2float(__ushort_as_half((ushort)(tfb[k] & 0xffffu)));
                const float qj = __half2float(__ushort_as_half((ushort)(tsb[k] & 0xffffu)));
                const int   mi = (int)(tfb[k] >> 16);
                const float d  = db[k];
                const float scr = (d < RADIUS) ? 0.5f * (1.0f + __cosf(d * c_rad)) : 0.0f;
                atomicAdd(&bins[mi], qi * qj * __fdividef(scr, d));
            }
        }
    }

    __syncthreads();
    float* p = partial + (size_t)blockIdx.x * n_mol;
    for (int m = threadIdx.x; m < n_mol; m += 256) p[m] = bins[m];
}

__global__ __launch_bounds__(256) void reduce_bins(const float* __restrict__ partial,
                                                   float* __restrict__ out,
                                                   int nblk, int nchunk, int n_mol) {
    int gid = blockIdx.x * 256 + threadIdx.x;
    if (gid >= n_mol * nchunk) return;
    int m   = gid % n_mol;
    int cix = gid / n_mol;
    int b0 = cix * 64;
    int b1 = min(nblk, b0 + 64);
    float s = 0.0f;
    for (int b = b0; b < b1; ++b) s += partial[(size_t)b * n_mol + m];
    atomicAdd(&out[m], 0.5f * ECONV * s);
}

extern "C" void kernel_launch(void* const* d_in, const int* in_sizes, int n_in,
                              void* d_out, int out_size, void* d_ws, size_t ws_size,
                              hipStream_t stream) {
    const float* charges     = (const float*)d_in[0];
    const float* pair_dist   = (const float*)d_in[1];
    const int*   pair_first  = (const int*)d_in[2];
    const int*   pair_second = (const int*)d_in[3];
    const int*   mol_index   = (const int*)d_in[4];
    const int n_atoms = in_sizes[0];
    const int n_pairs = in_sizes[1];
    const int n_mol   = out_size;
    const int nvec    = n_pairs >> 2;

    // ws: [tab: n_atoms u32][partial: nblk * n_mol f32]; probe sinks write
    // into the partial region (pair_bins overwrites it afterwards).
    unsigned* tab = (unsigned*)d_ws;
    size_t off = ((size_t)n_atoms * 4 + 255) & ~(size_t)255;
    float* partial = (float*)((char*)d_ws + off);
    size_t avail = ws_size > off ? ws_size - off : 0;
    int nblk = (int)(avail / ((size_t)n_mol * 4));
    if (nblk > 2048) nblk = 2048;
    if (nblk < 1) nblk = 1;

    prep_tab<<<(n_atoms + 255) / 256, 256, 0, stream>>>(charges, mol_index, tab, n_atoms);

    // ---- ablation probes (results discarded; sized > pair_bins for top-5)
    probe_streams<<<2048, 256, 0, stream>>>((const f4*)pair_dist,
                                            (const i4*)pair_first,
                                            (const i4*)pair_second,
                                            partial, nvec);
    probe_gather<<<2048, 256, 0, stream>>>((const f4*)pair_dist,
                                           (const i4*)pair_first,
                                           (const i4*)pair_second,
                                           tab, partial, nvec);

    // ---- production (v6)
    pair_bins<<<nblk, 256, 0, stream>>>((const f4*)pair_dist,
                                        (const i4*)pair_first,
                                        (const i4*)pair_second,
                                        tab, partial, nvec, n_mol);
    hipMemsetAsync(d_out, 0, (size_t)n_mol * sizeof(float), stream);
    int nchunk = (nblk + 63) / 64;
    int total = n_mol * nchunk;
    reduce_bins<<<(total + 255) / 256, 256, 0, stream>>>(partial, (float*)d_out,
                                                         nblk, nchunk, n_mol);
}